// Round 3
// baseline (214.531 us; speedup 1.0000x reference)
//
#include <hip/hip_runtime.h>
#include <hip/hip_bf16.h>

// Problem constants: b=8, lq=lk=2048, d=256
#define BB 8
#define LQ 2048
#define LK 2048
#define DD 256
#define OUT0_N (BB*LQ*DD)      // LN output elements; attn follows in d_out

typedef short s16x8 __attribute__((ext_vector_type(8)));
typedef float f32x4 __attribute__((ext_vector_type(4)));

__device__ __forceinline__ unsigned short f2b(float x){
  unsigned int u = __float_as_uint(x);
  u += 0x7fffu + ((u >> 16) & 1u);           // RNE
  return (unsigned short)(u >> 16);
}
__device__ __forceinline__ float b2f(unsigned short h){
  return __uint_as_float(((unsigned int)h) << 16);
}
__device__ __forceinline__ float ldf(const void* p, long i, int bf){
  return bf ? b2f(((const unsigned short*)p)[i]) : ((const float*)p)[i];
}
__device__ __forceinline__ s16x8 ld8(const void* p, long i, int bf){
  if (bf) return *(const s16x8*)((const unsigned short*)p + i);
  const float* f = (const float*)p + i;
  float4 a = *(const float4*)(f);
  float4 c = *(const float4*)(f + 4);
  s16x8 r;
  r[0]=(short)f2b(a.x); r[1]=(short)f2b(a.y); r[2]=(short)f2b(a.z); r[3]=(short)f2b(a.w);
  r[4]=(short)f2b(c.x); r[5]=(short)f2b(c.y); r[6]=(short)f2b(c.z); r[7]=(short)f2b(c.w);
  return r;
}
__device__ __forceinline__ float wsum(float v){
  #pragma unroll
  for (int o=32;o;o>>=1) v += __shfl_xor(v, o, 64);
  return v;
}
// LDS-only barrier: drain LDS ops, do NOT drain vmcnt (attn stores / vt loads
// stay in flight across iterations). sched_barrier pins code motion (rule #18).
__device__ __forceinline__ void bar_lds(){
  __builtin_amdgcn_sched_barrier(0);
  asm volatile("s_waitcnt lgkmcnt(0)" ::: "memory");
  __builtin_amdgcn_s_barrier();
  __builtin_amdgcn_sched_barrier(0);
}

// ---------------- K0: runtime dtype detection ----------------
// flags[0]=1 -> mask is 1-byte bools (else int32); flags[1]=1 -> floats are bf16
__global__ void k_detect(const void* q, const void* mask, int* flags){
  __shared__ int sb, sc;
  if (threadIdx.x == 0){ sb = 0; sc = 0; }
  __syncthreads();
  const unsigned int* mw = (const unsigned int*)mask;
  int any = 0;
  for (int i = threadIdx.x; i < 1024; i += 256) if (mw[i] > 1u) any = 1;
  if (any) atomicOr(&sb, 1);
  float x = fabsf(((const float*)q)[threadIdx.x]);
  if (x > 1e-6f && x < 100.0f) atomicAdd(&sc, 1);
  __syncthreads();
  if (threadIdx.x == 0){
    flags[0] = sb;
    flags[1] = (sc < 192) ? 1 : 0;
  }
}

// ---------------- K1: e[b,j] = exp(dot(k[b,j,:], w_k)) ----------------
__global__ __launch_bounds__(256) void k_sk(const void* kk, const void* sh,
                                            float* e, const int* flags){
  int bf = flags[1];
  int wid  = (blockIdx.x << 2) + (threadIdx.x >> 6);
  int lane = threadIdx.x & 63;
  long base = (long)wid * DD + lane * 4;
  float acc;
  if (bf){
    ushort4 kv = *(const ushort4*)((const unsigned short*)kk + base);
    ushort4 wv = *(const ushort4*)((const unsigned short*)sh + DD + lane*4);
    acc = b2f(kv.x)*b2f(wv.x) + b2f(kv.y)*b2f(wv.y)
        + b2f(kv.z)*b2f(wv.z) + b2f(kv.w)*b2f(wv.w);
  } else {
    float4 kv = *(const float4*)((const float*)kk + base);
    float4 wv = *(const float4*)((const float*)sh + DD + lane*4);
    acc = kv.x*wv.x + kv.y*wv.y + kv.z*wv.z + kv.w*wv.w;
  }
  acc = wsum(acc);
  if (lane == 0) e[wid] = __expf(acc);
}

// ---------------- K1b: vt[b][d][j] = sum_e fc_w[d][e] * v[b,j,e]  (bf16) ----------------
__global__ __launch_bounds__(256) void k_vt(const void* v, const void* fc,
                                            unsigned short* vt, const int* flags){
  int bf = flags[1];
  int wid  = (blockIdx.x << 2) + (threadIdx.x >> 6);
  int lane = threadIdx.x & 63;
  int dbase = (wid & 15) << 4;
  int jbase = (wid >> 4) << 6;
  int r = lane & 15, g = lane >> 4;
  f32x4 acc[4];
  #pragma unroll
  for (int t2=0;t2<4;t2++) acc[t2] = (f32x4){0.f,0.f,0.f,0.f};
  #pragma unroll
  for (int ks = 0; ks < 8; ++ks){
    int k0 = ks*32 + g*8;
    s16x8 a = ld8(fc, (long)(dbase + r)*DD + k0, bf);
    #pragma unroll
    for (int t2 = 0; t2 < 4; ++t2){
      s16x8 bq = ld8(v, (long)(jbase + t2*16 + r)*DD + k0, bf);
      acc[t2] = __builtin_amdgcn_mfma_f32_16x16x32_bf16(a, bq, acc[t2], 0, 0, 0);
    }
  }
  int bidx = jbase >> 11;
  int jj   = jbase & 2047;
  long vb  = (long)bidx * DD * LK;
  #pragma unroll
  for (int t2 = 0; t2 < 4; ++t2){
    #pragma unroll
    for (int reg = 0; reg < 4; ++reg){
      int d = dbase + g*4 + reg;
      int j = jj + t2*16 + r;
      vt[vb + (long)d*LK + j] = f2b(acc[t2][reg]);
    }
  }
}

// ---------------- K2: fully fused: mask->bits, row scales, p-gen+attn-write,
//                  PV GEMM, residual, LayerNorm ----------------
// BM=32 x BN=256 per block, 512 threads (8 waves as 2x4, wave tile 16x64).
// grid 512 = 8 batches x 64 row-tiles, XCD-swizzled so each XCD owns 1 batch.
__global__ __launch_bounds__(512) void k_pvf(void* d_out, const unsigned short* vt,
    const void* q, const void* gamp, const void* betp,
    const void* mask, const float* e, const int* flags){
  __shared__ __align__(16) unsigned short As[2][32][72];  // p tile dbuf (9.2 KB)
  __shared__ unsigned int bits_s[32*64];                  // mask bits (8 KB)
  __shared__ float4 e_s4[512];                            // e row (8 KB)
  __shared__ float scale_s[32];
  __shared__ float psum[4][32], psq[4][32];
  __shared__ float mu_s[32], rs_s[32];
  __shared__ float gs[256], bs[256];
  int mbytes = flags[0], bf = flags[1];
  // bijective XCD swizzle: nwg=512, XCD x gets orig ids x*64..x*64+63 = batch x
  int o     = ((blockIdx.x & 7) << 6) + (blockIdx.x >> 3);
  int b     = o >> 6;
  int rbase = (o & 63) << 5;
  int t = threadIdx.x, lane = t & 63, wid = t >> 6;
  int wr = wid >> 2, wc = wid & 3;
  int r16 = lane >> 4, c16 = lane & 15;
  if (t < 256){ gs[t] = ldf(gamp, t, bf); bs[t] = ldf(betp, t, bf); }
  const float* eb = e + b * LK;
  e_s4[t] = ((const float4*)eb)[t];                        // stage e row
  const float* e_s = (const float*)e_s4;

  // ---- phase 0: read mask window ONCE, pack to bits in LDS ----
  long mbase = ((long)b*LQ + rbase) * (long)LK;            // element offset
  #pragma unroll
  for (int i = 0; i < 4; ++i){
    int w = t + (i << 9);                                  // bit-word 0..2047
    unsigned int bw = 0;
    if (mbytes){
      const unsigned long long* mq =
        (const unsigned long long*)((const unsigned char*)mask + mbase + (long)w*32);
      #pragma unroll
      for (int qq = 0; qq < 4; ++qq){
        unsigned long long m8 = mq[qq];
        #pragma unroll
        for (int c = 0; c < 8; ++c)
          bw |= (unsigned int)((m8 >> (8*c)) & 1ull) << (qq*8 + c);
      }
    } else {
      const int4* ip = (const int4*)((const int*)mask + mbase + (long)w*32);
      #pragma unroll
      for (int qq = 0; qq < 8; ++qq){
        int4 m4 = ip[qq];
        bw |= ((m4.x?1u:0u) << (qq*4)) | ((m4.y?1u:0u) << (qq*4+1))
            | ((m4.z?1u:0u) << (qq*4+2)) | ((m4.w?1u:0u) << (qq*4+3));
      }
    }
    bits_s[w] = bw;
  }
  __syncthreads();
  // ---- row scales: wave wid handles rows wid*4..+4 ----
  #pragma unroll
  for (int rr = 0; rr < 4; ++rr){
    int row = (wid << 2) + rr;
    unsigned int bw = bits_s[(row << 6) + lane];           // lane's 32 elements
    float s = 0.f;
    #pragma unroll
    for (int cc = 0; cc < 8; ++cc){
      float4 e4 = e_s4[(lane << 3) + cc];
      if (!((bw >> (4*cc  )) & 1u)) s += e4.x;
      if (!((bw >> (4*cc+1)) & 1u)) s += e4.y;
      if (!((bw >> (4*cc+2)) & 1u)) s += e4.z;
      if (!((bw >> (4*cc+3)) & 1u)) s += e4.w;
    }
    s = wsum(s);
    if (lane == 0) scale_s[row] = (s > 0.f) ? (1.0f/s) : -1.0f;
  }
  __syncthreads();

  // ---- main fused loop ----
  int prow = t >> 4, q15 = t & 15;                         // p-gen: 4 elems/thread
  long arow = ((long)b*LQ + rbase + prow) * (long)LK;
  float scal = scale_s[prow];
  unsigned short* attn16 = (unsigned short*)d_out + OUT0_N;
  float*          attn32 = (float*)d_out + OUT0_N;
  const unsigned short* vtb = vt + (long)b * DD * LK;

  f32x4 acc[4];
  #pragma unroll
  for (int j=0;j<4;j++) acc[j] = (f32x4){0.f,0.f,0.f,0.f};
  s16x8 B0[8], B1[8];

  auto BLOAD = [&](int tt, s16x8* Bv){
    int k0 = tt << 6;
    #pragma unroll
    for (int ni = 0; ni < 4; ++ni){
      long cb = (long)(wc*64 + ni*16 + c16) * LK + k0 + r16*8;
      Bv[ni*2+0] = *(const s16x8*)(vtb + cb);
      Bv[ni*2+1] = *(const s16x8*)(vtb + cb + 32);
    }
  };
  auto PGEN = [&](int tt, int buf){
    int j0 = (tt << 6) + (q15 << 2);
    unsigned int bw = bits_s[(prow << 6) + (j0 >> 5)];
    int sh4 = j0 & 31;
    float4 e4 = *(const float4*)(&e_s[j0]);
    float p0,p1,p2,p3;
    if (scal < 0.f){
      p0 = p1 = p2 = p3 = (1.0f/2048.0f);
    } else {
      p0 = ((bw >> (sh4  )) & 1u) ? 0.f : e4.x * scal;
      p1 = ((bw >> (sh4+1)) & 1u) ? 0.f : e4.y * scal;
      p2 = ((bw >> (sh4+2)) & 1u) ? 0.f : e4.z * scal;
      p3 = ((bw >> (sh4+3)) & 1u) ? 0.f : e4.w * scal;
    }
    ushort4 w4; w4.x=f2b(p0); w4.y=f2b(p1); w4.z=f2b(p2); w4.w=f2b(p3);
    *(ushort4*)(&As[buf][prow][q15 << 2]) = w4;
    if (bf){
      *(ushort4*)(attn16 + arow + j0) = w4;
    } else {
      float4 o4 = {p0,p1,p2,p3};
      *(float4*)(attn32 + arow + j0) = o4;
    }
  };
  auto COMPUTE = [&](int buf, s16x8* Bv){
    #pragma unroll
    for (int kg = 0; kg < 2; ++kg){
      int ko = kg*32 + r16*8;
      s16x8 a0 = *(const s16x8*)(&As[buf][wr*16 + c16][ko]);
      #pragma unroll
      for (int ni = 0; ni < 4; ++ni)
        acc[ni] = __builtin_amdgcn_mfma_f32_16x16x32_bf16(a0, Bv[ni*2+kg], acc[ni], 0,0,0);
    }
  };

  PGEN(0, 0); BLOAD(0, B0);
  bar_lds();
  #pragma unroll 1
  for (int tt = 0; tt < 32; tt += 2){
    BLOAD(tt+1, B1); PGEN(tt+1, 1);
    COMPUTE(0, B0);
    bar_lds();
    if (tt + 2 < 32){ BLOAD(tt+2, B0); PGEN(tt+2, 0); }
    COMPUTE(1, B1);
    bar_lds();
  }

  // ---- epilogue: residual + LayerNorm ----
  #pragma unroll
  for (int reg = 0; reg < 4; ++reg){
    int rl = wr*16 + r16*4 + reg;
    long grow = (long)b*LQ + rbase + rl;
    float ps = 0.f, pq = 0.f;
    #pragma unroll
    for (int ni = 0; ni < 4; ++ni){
      int col = wc*64 + ni*16 + c16;
      float x = acc[ni][reg] + ldf(q, grow*(long)DD + col, bf);
      acc[ni][reg] = x;
      ps += x; pq += x*x;
    }
    ps += __shfl_xor(ps, 1, 64); pq += __shfl_xor(pq, 1, 64);
    ps += __shfl_xor(ps, 2, 64); pq += __shfl_xor(pq, 2, 64);
    ps += __shfl_xor(ps, 4, 64); pq += __shfl_xor(pq, 4, 64);
    ps += __shfl_xor(ps, 8, 64); pq += __shfl_xor(pq, 8, 64);
    if (c16 == 0){ psum[wc][rl] = ps; psq[wc][rl] = pq; }
  }
  __syncthreads();
  if (t < 32){
    float s  = psum[0][t] + psum[1][t] + psum[2][t] + psum[3][t];
    float s2 = psq [0][t] + psq [1][t] + psq [2][t] + psq [3][t];
    float mu = s * (1.0f/256.0f);
    float var = s2 * (1.0f/256.0f) - mu*mu;
    mu_s[t] = mu;
    rs_s[t] = rsqrtf(var + 1e-5f);
  }
  __syncthreads();
  #pragma unroll
  for (int ni = 0; ni < 4; ++ni){
    int col = wc*64 + ni*16 + c16;
    float g = gs[col], be = bs[col];
    #pragma unroll
    for (int reg = 0; reg < 4; ++reg){
      int rl = wr*16 + r16*4 + reg;
      float y = (acc[ni][reg] - mu_s[rl]) * rs_s[rl] * g + be;
      long oi = ((long)b*LQ + rbase + rl)*(long)DD + col;
      if (bf) ((unsigned short*)d_out)[oi] = f2b(y);
      else    ((float*)d_out)[oi] = y;
    }
  }
}

extern "C" void kernel_launch(void* const* d_in, const int* in_sizes, int n_in,
                              void* d_out, int out_size, void* d_ws, size_t ws_size,
                              hipStream_t stream) {
  const void* q    = d_in[0];
  const void* k    = d_in[1];
  const void* v    = d_in[2];
  const void* sh   = d_in[3];
  const void* fc   = d_in[4];
  const void* gam  = d_in[5];
  const void* bet  = d_in[6];
  const void* mask = d_in[7];

  int*            flags = (int*)d_ws;
  float*          e     = (float*)((char*)d_ws + 1024);            // 16384 f32
  unsigned short* vt    = (unsigned short*)((char*)d_ws + 262144); // 8.4 MB bf16

  k_detect<<<1,    256, 0, stream>>>(q, mask, flags);
  k_sk    <<<4096, 256, 0, stream>>>(k, sh, e, flags);
  k_vt    <<<1024, 256, 0, stream>>>(v, fc, vt, flags);
  k_pvf   <<<512,  512, 0, stream>>>(d_out, vt, q, gam, bet, mask, e, flags);
}

// Round 4
// 189.465 us; speedup vs baseline: 1.1323x; 1.1323x over previous
//
#include <hip/hip_runtime.h>
#include <hip/hip_bf16.h>

// Problem constants: b=8, lq=lk=2048, d=256
#define BB 8
#define LQ 2048
#define LK 2048
#define DD 256
#define OUT0_N (BB*LQ*DD)      // LN output elements; attn follows in d_out

typedef short s16x8 __attribute__((ext_vector_type(8)));
typedef float f32x4 __attribute__((ext_vector_type(4)));

__device__ __forceinline__ unsigned short f2b(float x){
  unsigned int u = __float_as_uint(x);
  u += 0x7fffu + ((u >> 16) & 1u);           // RNE
  return (unsigned short)(u >> 16);
}
__device__ __forceinline__ float b2f(unsigned short h){
  return __uint_as_float(((unsigned int)h) << 16);
}
__device__ __forceinline__ float ldf(const void* p, long i, int bf){
  return bf ? b2f(((const unsigned short*)p)[i]) : ((const float*)p)[i];
}
__device__ __forceinline__ s16x8 ld8(const void* p, long i, int bf){
  if (bf) return *(const s16x8*)((const unsigned short*)p + i);
  const float* f = (const float*)p + i;
  float4 a = *(const float4*)(f);
  float4 c = *(const float4*)(f + 4);
  s16x8 r;
  r[0]=(short)f2b(a.x); r[1]=(short)f2b(a.y); r[2]=(short)f2b(a.z); r[3]=(short)f2b(a.w);
  r[4]=(short)f2b(c.x); r[5]=(short)f2b(c.y); r[6]=(short)f2b(c.z); r[7]=(short)f2b(c.w);
  return r;
}
__device__ __forceinline__ float wsum(float v){
  #pragma unroll
  for (int o=32;o;o>>=1) v += __shfl_xor(v, o, 64);
  return v;
}

// ---------------- K0: runtime dtype detection ----------------
// flags[0]=1 -> mask is 1-byte bools (else int32); flags[1]=1 -> floats are bf16
__global__ void k_detect(const void* q, const void* mask, int* flags){
  __shared__ int sb, sc;
  if (threadIdx.x == 0){ sb = 0; sc = 0; }
  __syncthreads();
  const unsigned int* mw = (const unsigned int*)mask;
  int any = 0;
  for (int i = threadIdx.x; i < 1024; i += 256) if (mw[i] > 1u) any = 1;
  if (any) atomicOr(&sb, 1);
  float x = fabsf(((const float*)q)[threadIdx.x]);
  if (x > 1e-6f && x < 100.0f) atomicAdd(&sc, 1);
  __syncthreads();
  if (threadIdx.x == 0){
    flags[0] = sb;
    flags[1] = (sc < 192) ? 1 : 0;
  }
}

// ---------------- K1: e[b,j] = exp(dot(k[b,j,:], w_k)) ----------------
__global__ __launch_bounds__(256) void k_sk(const void* kk, const void* sh,
                                            float* e, const int* flags){
  int bf = flags[1];
  int wid  = (blockIdx.x << 2) + (threadIdx.x >> 6);
  int lane = threadIdx.x & 63;
  long base = (long)wid * DD + lane * 4;
  float acc;
  if (bf){
    ushort4 kv = *(const ushort4*)((const unsigned short*)kk + base);
    ushort4 wv = *(const ushort4*)((const unsigned short*)sh + DD + lane*4);
    acc = b2f(kv.x)*b2f(wv.x) + b2f(kv.y)*b2f(wv.y)
        + b2f(kv.z)*b2f(wv.z) + b2f(kv.w)*b2f(wv.w);
  } else {
    float4 kv = *(const float4*)((const float*)kk + base);
    float4 wv = *(const float4*)((const float*)sh + DD + lane*4);
    acc = kv.x*wv.x + kv.y*wv.y + kv.z*wv.z + kv.w*wv.w;
  }
  acc = wsum(acc);
  if (lane == 0) e[wid] = __expf(acc);
}

// ---------------- K1b: vtf[b][kk][d][8] = (fc_w @ v^T) fragment-major bf16 ----
// C[j][d] = sum_e v[j,e]*fc[d,e]; A=v (M=j), B=fc (N=d). Fragment-major layout:
// element (b, j, d) lives at ((b*256 + (j>>3))*256 + d)*8 + (j&7).
__global__ __launch_bounds__(256) void k_vt(const void* v, const void* fc,
                                            unsigned short* vtf, const int* flags){
  int bf = flags[1];
  int wid  = (blockIdx.x << 2) + (threadIdx.x >> 6);   // 0..4095
  int lane = threadIdx.x & 63;
  int dbase = (wid & 15) << 4;     // 16 d (N) per wave
  int jbase = (wid >> 4) << 6;     // 64 j (M) per wave, within one batch
  int r = lane & 15, g = lane >> 4;
  f32x4 acc[4];
  #pragma unroll
  for (int t2=0;t2<4;t2++) acc[t2] = (f32x4){0.f,0.f,0.f,0.f};
  #pragma unroll
  for (int ks = 0; ks < 8; ++ks){
    int k0 = ks*32 + g*8;
    s16x8 bv = ld8(fc, (long)(dbase + r)*DD + k0, bf);     // B: col d = lane&15
    #pragma unroll
    for (int t2 = 0; t2 < 4; ++t2){
      s16x8 a = ld8(v, (long)(jbase + t2*16 + r)*DD + k0, bf);  // A: row j = lane&15
      acc[t2] = __builtin_amdgcn_mfma_f32_16x16x32_bf16(a, bv, acc[t2], 0, 0, 0);
    }
  }
  int b  = jbase >> 11;
  int jj = jbase & 2047;
  int d  = dbase + r;                      // C col = lane&15
  #pragma unroll
  for (int t2 = 0; t2 < 4; ++t2){
    int kk = (jj >> 3) + t2*2 + (g >> 1);  // j = jj + t2*16 + g*4 + reg
    long idx = ((long)(b*256 + kk))*2048 + (long)d*8 + (g & 1)*4;
    ushort4 w4;
    w4.x = f2b(acc[t2][0]); w4.y = f2b(acc[t2][1]);
    w4.z = f2b(acc[t2][2]); w4.w = f2b(acc[t2][3]);
    *(ushort4*)(vtf + idx) = w4;
  }
}

// ---------------- K2: mask -> attn(f32/bf16 out) + packed bits + row scales ----
// One wave per row; the ONLY full mask read in the pipeline. Pure streaming.
__global__ __launch_bounds__(256) void k_pack(const void* mask, const float* e,
    void* d_out, unsigned int* bits, float* scale, const int* flags){
  int mbytes = flags[0], bf = flags[1];
  int row  = (blockIdx.x << 2) + (threadIdx.x >> 6);   // 0..16383
  int lane = threadIdx.x & 63;
  int b = row >> 11;
  const float* eb = e + b * LK;
  long rowm = (long)row * LK;
  // lane covers elements j = lane*32 .. +31
  unsigned int bw = 0;
  if (mbytes){
    const unsigned long long* mq =
      (const unsigned long long*)((const unsigned char*)mask + rowm + lane*32);
    #pragma unroll
    for (int qq = 0; qq < 4; ++qq){
      unsigned long long m8 = mq[qq];
      #pragma unroll
      for (int c = 0; c < 8; ++c)
        bw |= (unsigned int)((m8 >> (8*c)) & 1ull) << (qq*8 + c);
    }
  } else {
    const int4* ip = (const int4*)((const int*)mask + rowm + (long)lane*32);
    #pragma unroll
    for (int w = 0; w < 8; ++w){
      int4 m4 = ip[w];
      bw |= ((m4.x?1u:0u) << (w*4)) | ((m4.y?1u:0u) << (w*4+1))
          | ((m4.z?1u:0u) << (w*4+2)) | ((m4.w?1u:0u) << (w*4+3));
    }
  }
  float4 ev[8];
  float s = 0.f;
  #pragma unroll
  for (int w = 0; w < 8; ++w){
    ev[w] = *(const float4*)(eb + lane*32 + w*4);
    if (!((bw >> (w*4  )) & 1u)) s += ev[w].x;
    if (!((bw >> (w*4+1)) & 1u)) s += ev[w].y;
    if (!((bw >> (w*4+2)) & 1u)) s += ev[w].z;
    if (!((bw >> (w*4+3)) & 1u)) s += ev[w].w;
  }
  s = wsum(s);
  float scal = (s > 0.f) ? (1.0f/s) : -1.0f;
  if (lane == 0){ scale[row] = scal; bits[(long)row*64 + 0] = bw; }
  if (lane != 0) bits[(long)row*64 + lane] = bw;
  // write attn row segment
  #pragma unroll
  for (int w = 0; w < 8; ++w){
    float p0,p1,p2,p3;
    if (scal < 0.f){ p0=p1=p2=p3 = 1.0f/2048.0f; }
    else {
      p0 = ((bw >> (w*4  )) & 1u) ? 0.f : ev[w].x * scal;
      p1 = ((bw >> (w*4+1)) & 1u) ? 0.f : ev[w].y * scal;
      p2 = ((bw >> (w*4+2)) & 1u) ? 0.f : ev[w].z * scal;
      p3 = ((bw >> (w*4+3)) & 1u) ? 0.f : ev[w].w * scal;
    }
    if (bf){
      ushort4 u4; u4.x=f2b(p0); u4.y=f2b(p1); u4.z=f2b(p2); u4.w=f2b(p3);
      *(ushort4*)((unsigned short*)d_out + OUT0_N + rowm + lane*32 + w*4) = u4;
    } else {
      float4 f4 = {p0,p1,p2,p3};
      *(float4*)((float*)d_out + OUT0_N + rowm + (long)lane*32 + w*4) = f4;
    }
  }
}

// ---------------- K3: PV GEMM (p regenerated from bits+e) + residual + LN ----
// BM=32 x BN=256 per block, 512 threads (8 waves 2x4, wave tile 16x64), BK=64.
__global__ __launch_bounds__(512) void k_pvf(void* d_out, const unsigned short* vtf,
    const void* q, const void* gamp, const void* betp,
    const unsigned int* bits, const float* e, const float* scaleg, const int* flags){
  __shared__ __align__(16) unsigned short As[2][32][72];  // p tile dbuf
  __shared__ float4 e_s4[512];                            // e row (8 KB)
  __shared__ unsigned int bits_s[32*64];                  // 8 KB
  __shared__ float scale_s[32];
  __shared__ float psum[4][32], psq[4][32];
  __shared__ float mu_s[32], rs_s[32];
  __shared__ float gs[256], bs[256];
  int bf = flags[1];
  // bijective XCD swizzle: 512 wgs -> XCD x owns batch x
  int o     = ((blockIdx.x & 7) << 6) + (blockIdx.x >> 3);
  int b     = o >> 6;
  int rbase = (o & 63) << 5;
  int t = threadIdx.x, lane = t & 63, wid = t >> 6;
  int wr = wid >> 2, wc = wid & 3;
  int r16 = lane >> 4, c16 = lane & 15;
  if (t < 256){ gs[t] = ldf(gamp, t, bf); bs[t] = ldf(betp, t, bf); }
  e_s4[t] = ((const float4*)(e + b * LK))[t];
  const float* e_s = (const float*)e_s4;
  {
    long wbase = ((long)b*LQ + rbase) * 64;
    *(int4*)(&bits_s[t*4]) = *(const int4*)(bits + wbase + t*4);
    if (t < 32) scale_s[t] = scaleg[(long)b*LQ + rbase + t];
  }
  __syncthreads();

  int prow = t >> 4, q15 = t & 15;
  float scal = scale_s[prow];
  const unsigned short* vtfb = vtf + (long)b * 256 * 2048;

  f32x4 acc[4];
  #pragma unroll
  for (int j=0;j<4;j++) acc[j] = (f32x4){0.f,0.f,0.f,0.f};
  s16x8 B0[8], B1[8];

  auto BLOAD = [&](int tt, s16x8* Bv){
    // fragment (d = wc*64+ni*16+c16, k = tt*64 + kg*32 + r16*8)
    #pragma unroll
    for (int ni = 0; ni < 4; ++ni){
      int d = wc*64 + ni*16 + c16;
      const unsigned short* p0 = vtfb + (long)(tt*8 + r16)*2048 + d*8;
      Bv[ni*2+0] = *(const s16x8*)(p0);
      Bv[ni*2+1] = *(const s16x8*)(p0 + 4*2048);
    }
  };
  auto PGEN = [&](int tt, int buf){
    int j0 = (tt << 6) + (q15 << 2);
    unsigned int bw = bits_s[(prow << 6) + (j0 >> 5)];
    int sh4 = j0 & 31;
    float4 e4 = *(const float4*)(&e_s[j0]);
    float p0,p1,p2,p3;
    if (scal < 0.f){
      p0 = p1 = p2 = p3 = (1.0f/2048.0f);
    } else {
      p0 = ((bw >> (sh4  )) & 1u) ? 0.f : e4.x * scal;
      p1 = ((bw >> (sh4+1)) & 1u) ? 0.f : e4.y * scal;
      p2 = ((bw >> (sh4+2)) & 1u) ? 0.f : e4.z * scal;
      p3 = ((bw >> (sh4+3)) & 1u) ? 0.f : e4.w * scal;
    }
    ushort4 w4; w4.x=f2b(p0); w4.y=f2b(p1); w4.z=f2b(p2); w4.w=f2b(p3);
    *(ushort4*)(&As[buf][prow][q15 << 2]) = w4;
  };
  auto COMPUTE = [&](int buf, s16x8* Bv){
    #pragma unroll
    for (int kg = 0; kg < 2; ++kg){
      int ko = kg*32 + r16*8;
      s16x8 a0 = *(const s16x8*)(&As[buf][wr*16 + c16][ko]);
      #pragma unroll
      for (int ni = 0; ni < 4; ++ni)
        acc[ni] = __builtin_amdgcn_mfma_f32_16x16x32_bf16(a0, Bv[ni*2+kg], acc[ni], 0,0,0);
    }
  };

  PGEN(0, 0); BLOAD(0, B0);
  __syncthreads();
  #pragma unroll 1
  for (int tt = 0; tt < 32; tt += 2){
    BLOAD(tt+1, B1); PGEN(tt+1, 1);
    COMPUTE(0, B0);
    __syncthreads();
    if (tt + 2 < 32){ BLOAD(tt+2, B0); PGEN(tt+2, 0); }
    COMPUTE(1, B1);
    __syncthreads();
  }

  // ---- epilogue: residual + LayerNorm ----
  #pragma unroll
  for (int reg = 0; reg < 4; ++reg){
    int rl = wr*16 + r16*4 + reg;
    long grow = (long)b*LQ + rbase + rl;
    float ps = 0.f, pq = 0.f;
    #pragma unroll
    for (int ni = 0; ni < 4; ++ni){
      int col = wc*64 + ni*16 + c16;
      float x = acc[ni][reg] + ldf(q, grow*(long)DD + col, bf);
      acc[ni][reg] = x;
      ps += x; pq += x*x;
    }
    ps += __shfl_xor(ps, 1, 64); pq += __shfl_xor(pq, 1, 64);
    ps += __shfl_xor(ps, 2, 64); pq += __shfl_xor(pq, 2, 64);
    ps += __shfl_xor(ps, 4, 64); pq += __shfl_xor(pq, 4, 64);
    ps += __shfl_xor(ps, 8, 64); pq += __shfl_xor(pq, 8, 64);
    if (c16 == 0){ psum[wc][rl] = ps; psq[wc][rl] = pq; }
  }
  __syncthreads();
  if (t < 32){
    float s  = psum[0][t] + psum[1][t] + psum[2][t] + psum[3][t];
    float s2 = psq [0][t] + psq [1][t] + psq [2][t] + psq [3][t];
    float mu = s * (1.0f/256.0f);
    float var = s2 * (1.0f/256.0f) - mu*mu;
    mu_s[t] = mu;
    rs_s[t] = rsqrtf(var + 1e-5f);
  }
  __syncthreads();
  #pragma unroll
  for (int ni = 0; ni < 4; ++ni){
    int col = wc*64 + ni*16 + c16;
    float g = gs[col], be = bs[col];
    #pragma unroll
    for (int reg = 0; reg < 4; ++reg){
      int rl = wr*16 + r16*4 + reg;
      float y = (acc[ni][reg] - mu_s[rl]) * rs_s[rl] * g + be;
      long oi = ((long)b*LQ + rbase + rl)*(long)DD + col;
      if (bf) ((unsigned short*)d_out)[oi] = f2b(y);
      else    ((float*)d_out)[oi] = y;
    }
  }
}

extern "C" void kernel_launch(void* const* d_in, const int* in_sizes, int n_in,
                              void* d_out, int out_size, void* d_ws, size_t ws_size,
                              hipStream_t stream) {
  const void* q    = d_in[0];
  const void* k    = d_in[1];
  const void* v    = d_in[2];
  const void* sh   = d_in[3];
  const void* fc   = d_in[4];
  const void* gam  = d_in[5];
  const void* bet  = d_in[6];
  const void* mask = d_in[7];

  int*            flags = (int*)d_ws;
  float*          e     = (float*)((char*)d_ws + 65536);     // 64 KB
  float*          scale = (float*)((char*)d_ws + 131072);    // 64 KB
  unsigned int*   bits  = (unsigned int*)((char*)d_ws + 196608);   // 4 MB
  unsigned short* vtf   = (unsigned short*)((char*)d_ws + 4456448); // 8.4 MB

  k_detect<<<1,    256, 0, stream>>>(q, mask, flags);
  k_sk    <<<4096, 256, 0, stream>>>(k, sh, e, flags);
  k_vt    <<<1024, 256, 0, stream>>>(v, fc, vtf, flags);
  k_pack  <<<4096, 256, 0, stream>>>(mask, e, d_out, bits, scale, flags);
  k_pvf   <<<512,  512, 0, stream>>>(d_out, vtf, q, gam, bet, bits, e, scale, flags);
}

// Round 5
// 162.148 us; speedup vs baseline: 1.3231x; 1.1685x over previous
//
#include <hip/hip_runtime.h>
#include <hip/hip_bf16.h>

// Problem constants: b=8, lq=lk=2048, d=256
#define BB 8
#define LQ 2048
#define LK 2048
#define DD 256
#define OUT0_N (BB*LQ*DD)      // LN output elements; attn follows in d_out

typedef short s16x8 __attribute__((ext_vector_type(8)));
typedef float f32x4 __attribute__((ext_vector_type(4)));

__device__ __forceinline__ unsigned short f2b(float x){
  unsigned int u = __float_as_uint(x);
  u += 0x7fffu + ((u >> 16) & 1u);           // RNE
  return (unsigned short)(u >> 16);
}
__device__ __forceinline__ float b2f(unsigned short h){
  return __uint_as_float(((unsigned int)h) << 16);
}
__device__ __forceinline__ float ldf(const void* p, long i, int bf){
  return bf ? b2f(((const unsigned short*)p)[i]) : ((const float*)p)[i];
}
__device__ __forceinline__ s16x8 ld8(const void* p, long i, int bf){
  if (bf) return *(const s16x8*)((const unsigned short*)p + i);
  const float* f = (const float*)p + i;
  float4 a = *(const float4*)(f);
  float4 c = *(const float4*)(f + 4);
  s16x8 r;
  r[0]=(short)f2b(a.x); r[1]=(short)f2b(a.y); r[2]=(short)f2b(a.z); r[3]=(short)f2b(a.w);
  r[4]=(short)f2b(c.x); r[5]=(short)f2b(c.y); r[6]=(short)f2b(c.z); r[7]=(short)f2b(c.w);
  return r;
}
__device__ __forceinline__ float wsum(float v){
  #pragma unroll
  for (int o=32;o;o>>=1) v += __shfl_xor(v, o, 64);
  return v;
}

// ---------------- K0: runtime dtype detection ----------------
// flags[0]=1 -> mask is 1-byte bools (else int32); flags[1]=1 -> floats are bf16
__global__ void k_detect(const void* q, const void* mask, int* flags){
  __shared__ int sb, sc;
  if (threadIdx.x == 0){ sb = 0; sc = 0; }
  __syncthreads();
  const unsigned int* mw = (const unsigned int*)mask;
  int any = 0;
  for (int i = threadIdx.x; i < 1024; i += 256) if (mw[i] > 1u) any = 1;
  if (any) atomicOr(&sb, 1);
  float x = fabsf(((const float*)q)[threadIdx.x]);
  if (x > 1e-6f && x < 100.0f) atomicAdd(&sc, 1);
  __syncthreads();
  if (threadIdx.x == 0){
    flags[0] = sb;
    flags[1] = (sc < 192) ? 1 : 0;
  }
}

// ---------------- K1: e[b,j] = exp(dot(k[b,j,:], w_k)) ----------------
__global__ __launch_bounds__(256) void k_sk(const void* kk, const void* sh,
                                            float* e, const int* flags){
  int bf = flags[1];
  int wid  = (blockIdx.x << 2) + (threadIdx.x >> 6);
  int lane = threadIdx.x & 63;
  long base = (long)wid * DD + lane * 4;
  float acc;
  if (bf){
    ushort4 kv = *(const ushort4*)((const unsigned short*)kk + base);
    ushort4 wv = *(const ushort4*)((const unsigned short*)sh + DD + lane*4);
    acc = b2f(kv.x)*b2f(wv.x) + b2f(kv.y)*b2f(wv.y)
        + b2f(kv.z)*b2f(wv.z) + b2f(kv.w)*b2f(wv.w);
  } else {
    float4 kv = *(const float4*)((const float*)kk + base);
    float4 wv = *(const float4*)((const float*)sh + DD + lane*4);
    acc = kv.x*wv.x + kv.y*wv.y + kv.z*wv.z + kv.w*wv.w;
  }
  acc = wsum(acc);
  if (lane == 0) e[wid] = __expf(acc);
}

// ---------------- K1b: vtf[b][kk][d][8] = (fc_w @ v^T) fragment-major bf16 ----
// C[j][d] = sum_e v[j,e]*fc[d,e]; A=v (M=j), B=fc (N=d). Fragment-major layout:
// element (b, j, d) lives at ((b*256 + (j>>3))*256 + d)*8 + (j&7).
__global__ __launch_bounds__(256) void k_vt(const void* v, const void* fc,
                                            unsigned short* vtf, const int* flags){
  int bf = flags[1];
  int wid  = (blockIdx.x << 2) + (threadIdx.x >> 6);   // 0..4095
  int lane = threadIdx.x & 63;
  int dbase = (wid & 15) << 4;     // 16 d (N) per wave
  int jbase = (wid >> 4) << 6;     // 64 j (M) per wave, within one batch
  int r = lane & 15, g = lane >> 4;
  f32x4 acc[4];
  #pragma unroll
  for (int t2=0;t2<4;t2++) acc[t2] = (f32x4){0.f,0.f,0.f,0.f};
  #pragma unroll
  for (int ks = 0; ks < 8; ++ks){
    int k0 = ks*32 + g*8;
    s16x8 bv = ld8(fc, (long)(dbase + r)*DD + k0, bf);     // B: col d = lane&15
    #pragma unroll
    for (int t2 = 0; t2 < 4; ++t2){
      s16x8 a = ld8(v, (long)(jbase + t2*16 + r)*DD + k0, bf);  // A: row j = lane&15
      acc[t2] = __builtin_amdgcn_mfma_f32_16x16x32_bf16(a, bv, acc[t2], 0, 0, 0);
    }
  }
  int b  = jbase >> 11;
  int jj = jbase & 2047;
  int d  = dbase + r;                      // C col = lane&15
  #pragma unroll
  for (int t2 = 0; t2 < 4; ++t2){
    int kk = (jj >> 3) + t2*2 + (g >> 1);  // j = jj + t2*16 + g*4 + reg
    long idx = ((long)(b*256 + kk))*2048 + (long)d*8 + (g & 1)*4;
    ushort4 w4;
    w4.x = f2b(acc[t2][0]); w4.y = f2b(acc[t2][1]);
    w4.z = f2b(acc[t2][2]); w4.w = f2b(acc[t2][3]);
    *(ushort4*)(vtf + idx) = w4;
  }
}

// ---------------- K2: mask -> attn out + packed bits + row scales (COALESCED) ----
// One wave per row. Step w: lane owns elements w*256 + lane*4 .. +3 -> every
// wave instruction touches contiguous memory (mask 256B, e/attn 1KB).
// bits layout: bits[row*64 + lane] bit (w*4+c) = mask[row][w*256 + lane*4 + c].
__global__ __launch_bounds__(256) void k_pack(const void* mask, const float* e,
    void* d_out, unsigned int* bits, float* scale, const int* flags){
  int mbytes = flags[0], bf = flags[1];
  int row  = (blockIdx.x << 2) + (threadIdx.x >> 6);   // 0..16383
  int lane = threadIdx.x & 63;
  int b = row >> 11;
  const float* eb = e + b * LK;
  long rowm = (long)row * LK;
  unsigned int bw = 0;
  float4 ev[8];
  float s = 0.f;
  #pragma unroll
  for (int w = 0; w < 8; ++w){
    int j = (w << 8) + (lane << 2);
    unsigned int m4;
    if (mbytes){
      unsigned int mb = *(const unsigned int*)((const unsigned char*)mask + rowm + j);
      m4 = (mb & 1u) | ((mb >> 7) & 2u) | ((mb >> 14) & 4u) | ((mb >> 21) & 8u);
    } else {
      int4 mi = *(const int4*)((const int*)mask + rowm + j);
      m4 = (mi.x?1u:0u) | (mi.y?2u:0u) | (mi.z?4u:0u) | (mi.w?8u:0u);
    }
    bw |= m4 << (w*4);
    ev[w] = *(const float4*)(eb + j);
    if (!(m4 & 1u)) s += ev[w].x;
    if (!(m4 & 2u)) s += ev[w].y;
    if (!(m4 & 4u)) s += ev[w].z;
    if (!(m4 & 8u)) s += ev[w].w;
  }
  s = wsum(s);
  float scal = (s > 0.f) ? (1.0f/s) : -1.0f;
  bits[(long)row*64 + lane] = bw;
  if (lane == 0) scale[row] = scal;
  #pragma unroll
  for (int w = 0; w < 8; ++w){
    int j = (w << 8) + (lane << 2);
    float p0,p1,p2,p3;
    if (scal < 0.f){ p0=p1=p2=p3 = 1.0f/2048.0f; }
    else {
      p0 = (bw >> (w*4  )) & 1u ? 0.f : ev[w].x * scal;
      p1 = (bw >> (w*4+1)) & 1u ? 0.f : ev[w].y * scal;
      p2 = (bw >> (w*4+2)) & 1u ? 0.f : ev[w].z * scal;
      p3 = (bw >> (w*4+3)) & 1u ? 0.f : ev[w].w * scal;
    }
    if (bf){
      ushort4 u4; u4.x=f2b(p0); u4.y=f2b(p1); u4.z=f2b(p2); u4.w=f2b(p3);
      *(ushort4*)((unsigned short*)d_out + OUT0_N + rowm + j) = u4;
    } else {
      float4 f4 = {p0,p1,p2,p3};
      *(float4*)((float*)d_out + OUT0_N + rowm + j) = f4;
    }
  }
}

// ---------------- K3: PV GEMM (p regenerated from bits+e) + residual + LN ----
// BM=32 x BN=256 per block, 512 threads (8 waves 2x4, wave tile 16x64), BK=64.
__global__ __launch_bounds__(512) void k_pvf(void* d_out, const unsigned short* vtf,
    const void* q, const void* gamp, const void* betp,
    const unsigned int* bits, const float* e, const float* scaleg, const int* flags){
  __shared__ __align__(16) unsigned short As[2][32][72];  // p tile dbuf
  __shared__ float4 e_s4[512];                            // e row (8 KB)
  __shared__ unsigned int bits_s[32*64];                  // 8 KB
  __shared__ float scale_s[32];
  __shared__ float psum[4][32], psq[4][32];
  __shared__ float mu_s[32], rs_s[32];
  __shared__ float gs[256], bs[256];
  int bf = flags[1];
  // bijective XCD swizzle: 512 wgs -> XCD x owns batch x
  int o     = ((blockIdx.x & 7) << 6) + (blockIdx.x >> 3);
  int b     = o >> 6;
  int rbase = (o & 63) << 5;
  int t = threadIdx.x, lane = t & 63, wid = t >> 6;
  int wr = wid >> 2, wc = wid & 3;
  int r16 = lane >> 4, c16 = lane & 15;
  if (t < 256){ gs[t] = ldf(gamp, t, bf); bs[t] = ldf(betp, t, bf); }
  e_s4[t] = ((const float4*)(e + b * LK))[t];
  const float* e_s = (const float*)e_s4;
  {
    long wbase = ((long)b*LQ + rbase) * 64;
    *(int4*)(&bits_s[t*4]) = *(const int4*)(bits + wbase + t*4);
    if (t < 32) scale_s[t] = scaleg[(long)b*LQ + rbase + t];
  }
  __syncthreads();

  int prow = t >> 4, q15 = t & 15;
  float scal = scale_s[prow];
  const unsigned short* vtfb = vtf + (long)b * 256 * 2048;

  f32x4 acc[4];
  #pragma unroll
  for (int j=0;j<4;j++) acc[j] = (f32x4){0.f,0.f,0.f,0.f};
  s16x8 B0[8], B1[8];

  auto BLOAD = [&](int tt, s16x8* Bv){
    // fragment (d = wc*64+ni*16+c16, k = tt*64 + kg*32 + r16*8)
    #pragma unroll
    for (int ni = 0; ni < 4; ++ni){
      int d = wc*64 + ni*16 + c16;
      const unsigned short* p0 = vtfb + (long)(tt*8 + r16)*2048 + d*8;
      Bv[ni*2+0] = *(const s16x8*)(p0);
      Bv[ni*2+1] = *(const s16x8*)(p0 + 4*2048);
    }
  };
  auto PGEN = [&](int tt, int buf){
    int j0 = (tt << 6) + (q15 << 2);
    int g  = j0 >> 2;                         // element-block index
    unsigned int bw = bits_s[(prow << 6) + (g & 63)];
    int sh4 = (g >> 6) << 2;                  // nibble within the word
    float4 e4 = *(const float4*)(&e_s[j0]);
    float p0,p1,p2,p3;
    if (scal < 0.f){
      p0 = p1 = p2 = p3 = (1.0f/2048.0f);
    } else {
      p0 = ((bw >> (sh4  )) & 1u) ? 0.f : e4.x * scal;
      p1 = ((bw >> (sh4+1)) & 1u) ? 0.f : e4.y * scal;
      p2 = ((bw >> (sh4+2)) & 1u) ? 0.f : e4.z * scal;
      p3 = ((bw >> (sh4+3)) & 1u) ? 0.f : e4.w * scal;
    }
    ushort4 w4; w4.x=f2b(p0); w4.y=f2b(p1); w4.z=f2b(p2); w4.w=f2b(p3);
    *(ushort4*)(&As[buf][prow][q15 << 2]) = w4;
  };
  auto COMPUTE = [&](int buf, s16x8* Bv){
    #pragma unroll
    for (int kg = 0; kg < 2; ++kg){
      int ko = kg*32 + r16*8;
      s16x8 a0 = *(const s16x8*)(&As[buf][wr*16 + c16][ko]);
      #pragma unroll
      for (int ni = 0; ni < 4; ++ni)
        acc[ni] = __builtin_amdgcn_mfma_f32_16x16x32_bf16(a0, Bv[ni*2+kg], acc[ni], 0,0,0);
    }
  };

  PGEN(0, 0); BLOAD(0, B0);
  __syncthreads();
  #pragma unroll 1
  for (int tt = 0; tt < 32; tt += 2){
    BLOAD(tt+1, B1); PGEN(tt+1, 1);
    COMPUTE(0, B0);
    __syncthreads();
    if (tt + 2 < 32){ BLOAD(tt+2, B0); PGEN(tt+2, 0); }
    COMPUTE(1, B1);
    __syncthreads();
  }

  // ---- epilogue: residual + LayerNorm ----
  #pragma unroll
  for (int reg = 0; reg < 4; ++reg){
    int rl = wr*16 + r16*4 + reg;
    long grow = (long)b*LQ + rbase + rl;
    float ps = 0.f, pq = 0.f;
    #pragma unroll
    for (int ni = 0; ni < 4; ++ni){
      int col = wc*64 + ni*16 + c16;
      float x = acc[ni][reg] + ldf(q, grow*(long)DD + col, bf);
      acc[ni][reg] = x;
      ps += x; pq += x*x;
    }
    ps += __shfl_xor(ps, 1, 64); pq += __shfl_xor(pq, 1, 64);
    ps += __shfl_xor(ps, 2, 64); pq += __shfl_xor(pq, 2, 64);
    ps += __shfl_xor(ps, 4, 64); pq += __shfl_xor(pq, 4, 64);
    ps += __shfl_xor(ps, 8, 64); pq += __shfl_xor(pq, 8, 64);
    if (c16 == 0){ psum[wc][rl] = ps; psq[wc][rl] = pq; }
  }
  __syncthreads();
  if (t < 32){
    float s  = psum[0][t] + psum[1][t] + psum[2][t] + psum[3][t];
    float s2 = psq [0][t] + psq [1][t] + psq [2][t] + psq [3][t];
    float mu = s * (1.0f/256.0f);
    float var = s2 * (1.0f/256.0f) - mu*mu;
    mu_s[t] = mu;
    rs_s[t] = rsqrtf(var + 1e-5f);
  }
  __syncthreads();
  #pragma unroll
  for (int ni = 0; ni < 4; ++ni){
    int col = wc*64 + ni*16 + c16;
    float g = gs[col], be = bs[col];
    #pragma unroll
    for (int reg = 0; reg < 4; ++reg){
      int rl = wr*16 + r16*4 + reg;
      float y = (acc[ni][reg] - mu_s[rl]) * rs_s[rl] * g + be;
      long oi = ((long)b*LQ + rbase + rl)*(long)DD + col;
      if (bf) ((unsigned short*)d_out)[oi] = f2b(y);
      else    ((float*)d_out)[oi] = y;
    }
  }
}

extern "C" void kernel_launch(void* const* d_in, const int* in_sizes, int n_in,
                              void* d_out, int out_size, void* d_ws, size_t ws_size,
                              hipStream_t stream) {
  const void* q    = d_in[0];
  const void* k    = d_in[1];
  const void* v    = d_in[2];
  const void* sh   = d_in[3];
  const void* fc   = d_in[4];
  const void* gam  = d_in[5];
  const void* bet  = d_in[6];
  const void* mask = d_in[7];

  int*            flags = (int*)d_ws;
  float*          e     = (float*)((char*)d_ws + 65536);     // 64 KB
  float*          scale = (float*)((char*)d_ws + 131072);    // 64 KB
  unsigned int*   bits  = (unsigned int*)((char*)d_ws + 196608);   // 4 MB
  unsigned short* vtf   = (unsigned short*)((char*)d_ws + 4456448); // 8.4 MB

  k_detect<<<1,    256, 0, stream>>>(q, mask, flags);
  k_sk    <<<4096, 256, 0, stream>>>(k, sh, e, flags);
  k_vt    <<<1024, 256, 0, stream>>>(v, fc, vtf, flags);
  k_pack  <<<4096, 256, 0, stream>>>(mask, e, d_out, bits, scale, flags);
  k_pvf   <<<512,  512, 0, stream>>>(d_out, vtf, q, gam, bet, bits, e, scale, flags);
}